// Round 3
// baseline (46.560 us; speedup 1.0000x reference)
//
#include <hip/hip_runtime.h>

// KAN activation: out[b,c,h,w] = scale_base[c]*silu(x) + scale_sp[c]*spline_c(x) + bias[c]
// spline_c(x) = sum_k coef[c,k] * B_k(x), cubic B-splines on UNIFORM knots
// t_i = -2.2 + 0.4*i (i=0..11). For x in [t_j, t_{j+1}) (j=0..10), with local
// t = (x - t_j)/0.4, the spline is a cubic polynomial whose Horner coefficients
// are fixed linear combos of coef[c, j-3..j] (zero-padded outside [0,8)).
// Per-block (one channel per block) we precompute the 11 float4 coefficient
// vectors into LDS; slot 11 = zeros handles x outside [-2.2, 2.2).
//
// R3: nontemporal stores via clang ext_vector_type (HIP_vector_type rejected
// by __builtin_nontemporal_store). Goal: out stream doesn't allocate in L2/L3,
// x stays L3-resident across graph replays -> read-side HBM traffic ~0.

typedef float f32x4 __attribute__((ext_vector_type(4)));

constexpr int C_DIM   = 64;
constexpr int HW      = 128 * 128;   // elements per (b,c) plane
constexpr int NB      = 8;           // basis count
constexpr int THREADS = 256;
constexpr int VEC     = 4;
constexpr int ITERS   = HW / (THREADS * VEC);  // 16

__device__ __forceinline__ float kan_one(float xv, const float4* a_lds,
                                         float sb, float sp, float bi) {
    // silu(x) = x / (1 + exp(-x))
    float e    = __expf(-xv);
    float sig  = __builtin_amdgcn_rcpf(1.0f + e);
    float silu = xv * sig;

    // spline interval: u = (x + 2.2)/0.4 = 2.5x + 5.5
    float u  = fmaf(xv, 2.5f, 5.5f);
    float jf = floorf(u);
    float t  = u - jf;
    int   j  = (int)jf;
    bool valid = (u >= 0.0f) && (u < 11.0f);
    int   jj = valid ? j : 11;           // slot 11 is all-zero -> spline = 0
    float4 a = a_lds[jj];                // ds_read_b128
    float spl = fmaf(t, fmaf(t, fmaf(t, a.w, a.z), a.y), a.x);

    return fmaf(sb, silu, fmaf(sp, spl, bi));
}

__global__ __launch_bounds__(THREADS) void kan_kernel(
    const float* __restrict__ x,
    const float* __restrict__ coef,
    const float* __restrict__ scale_base,
    const float* __restrict__ scale_sp,
    const float* __restrict__ bias,
    float* __restrict__ out)
{
    __shared__ float4 a_lds[12];

    const int plane = blockIdx.x;        // b*C + c
    const int c     = plane & (C_DIM - 1);
    const int tid   = threadIdx.x;

    if (tid < 12) {
        float4 a = make_float4(0.0f, 0.0f, 0.0f, 0.0f);
        if (tid < 11) {
            // co[d] = coef[c, tid-3+d], zero-padded
            float co[4];
            #pragma unroll
            for (int d = 0; d < 4; ++d) {
                int idx = tid - 3 + d;
                co[d] = (idx >= 0 && idx < NB) ? coef[c * NB + idx] : 0.0f;
            }
            // uniform cubic B-spline -> Horner coefficients
            a.x = (co[0] + 4.0f * co[1] + co[2]) * (1.0f / 6.0f);
            a.y = (co[2] - co[0]) * 0.5f;
            a.z = (co[0] + co[2]) * 0.5f - co[1];
            a.w = (co[3] - co[0]) * (1.0f / 6.0f) + (co[1] - co[2]) * 0.5f;
        }
        a_lds[tid] = a;
    }
    const float sb = scale_base[c];
    const float sp = scale_sp[c];
    const float bi = bias[c];
    __syncthreads();

    const f32x4* __restrict__ xin =
        reinterpret_cast<const f32x4*>(x) + (size_t)plane * (HW / VEC);
    f32x4* __restrict__ xout =
        reinterpret_cast<f32x4*>(out) + (size_t)plane * (HW / VEC);

    #pragma unroll 4
    for (int it = 0; it < ITERS; ++it) {
        const int vi = it * THREADS + tid;
        f32x4 v = xin[vi];
        f32x4 r;
        r.x = kan_one(v.x, a_lds, sb, sp, bi);
        r.y = kan_one(v.y, a_lds, sb, sp, bi);
        r.z = kan_one(v.z, a_lds, sb, sp, bi);
        r.w = kan_one(v.w, a_lds, sb, sp, bi);
        __builtin_nontemporal_store(r, &xout[vi]);   // global_store_dwordx4 ... nt
    }
}

extern "C" void kernel_launch(void* const* d_in, const int* in_sizes, int n_in,
                              void* d_out, int out_size, void* d_ws, size_t ws_size,
                              hipStream_t stream) {
    const float* x          = (const float*)d_in[0];
    const float* coef       = (const float*)d_in[1];
    const float* scale_base = (const float*)d_in[2];
    const float* scale_sp   = (const float*)d_in[3];
    const float* bias       = (const float*)d_in[4];
    float* out              = (float*)d_out;

    const int planes = in_sizes[0] / HW;   // B*C = 2048
    kan_kernel<<<planes, THREADS, 0, stream>>>(x, coef, scale_base, scale_sp, bias, out);
}

// Round 4
// 45.369 us; speedup vs baseline: 1.0263x; 1.0263x over previous
//
#include <hip/hip_runtime.h>

// KAN activation: out[b,c,h,w] = scale_base[c]*silu(x) + scale_sp[c]*spline_c(x) + bias[c]
// spline_c(x) = sum_k coef[c,k] * B_k(x), cubic B-splines on UNIFORM knots
// t_i = -2.2 + 0.4*i (i=0..11). For x in [t_j, t_{j+1}) (j=0..10), with local
// t = (x - t_j)/0.4, the spline is a per-interval cubic whose Horner
// coefficients are fixed linear combos of coef[c, j-3..j] (zero-padded).
// Per-block (one channel) the 11 float4 coefficient vectors live in LDS;
// slot 11 = zeros handles x outside [-2.2, 2.2).
//
// R4: explicit 4-deep software pipeline (prologue loads 4 vectors; each body
// consumes one slot, issues the it+4 load into it, computes, stores) to keep
// 4 global loads in flight per wave at all times -> raise effective HBM BW
// from 4.15 TB/s toward the 6.3 TB/s copy ceiling.

typedef float f32x4 __attribute__((ext_vector_type(4)));

constexpr int C_DIM   = 64;
constexpr int HW      = 128 * 128;   // elements per (b,c) plane
constexpr int NB      = 8;           // basis count
constexpr int THREADS = 256;
constexpr int VEC     = 4;
constexpr int ITERS   = HW / (THREADS * VEC);  // 16
constexpr int PIPE    = 4;

__device__ __forceinline__ float kan_one(float xv, const float4* a_lds,
                                         float sb, float sp, float bi) {
    // silu(x) = x / (1 + exp(-x))
    float e    = __expf(-xv);
    float sig  = __builtin_amdgcn_rcpf(1.0f + e);
    float silu = xv * sig;

    // spline interval: u = (x + 2.2)/0.4 = 2.5x + 5.5
    float u  = fmaf(xv, 2.5f, 5.5f);
    float jf = floorf(u);
    float t  = u - jf;
    int   j  = (int)jf;
    bool valid = (u >= 0.0f) && (u < 11.0f);
    int   jj = valid ? j : 11;           // slot 11 is all-zero -> spline = 0
    float4 a = a_lds[jj];                // ds_read_b128
    float spl = fmaf(t, fmaf(t, fmaf(t, a.w, a.z), a.y), a.x);

    return fmaf(sb, silu, fmaf(sp, spl, bi));
}

__global__ __launch_bounds__(THREADS) void kan_kernel(
    const float* __restrict__ x,
    const float* __restrict__ coef,
    const float* __restrict__ scale_base,
    const float* __restrict__ scale_sp,
    const float* __restrict__ bias,
    float* __restrict__ out)
{
    __shared__ float4 a_lds[12];

    const int plane = blockIdx.x;        // b*C + c
    const int c     = plane & (C_DIM - 1);
    const int tid   = threadIdx.x;

    if (tid < 12) {
        float4 a = make_float4(0.0f, 0.0f, 0.0f, 0.0f);
        if (tid < 11) {
            // co[d] = coef[c, tid-3+d], zero-padded
            float co[4];
            #pragma unroll
            for (int d = 0; d < 4; ++d) {
                int idx = tid - 3 + d;
                co[d] = (idx >= 0 && idx < NB) ? coef[c * NB + idx] : 0.0f;
            }
            // uniform cubic B-spline -> Horner coefficients
            a.x = (co[0] + 4.0f * co[1] + co[2]) * (1.0f / 6.0f);
            a.y = (co[2] - co[0]) * 0.5f;
            a.z = (co[0] + co[2]) * 0.5f - co[1];
            a.w = (co[3] - co[0]) * (1.0f / 6.0f) + (co[1] - co[2]) * 0.5f;
        }
        a_lds[tid] = a;
    }
    const float sb = scale_base[c];
    const float sp = scale_sp[c];
    const float bi = bias[c];
    __syncthreads();

    const f32x4* __restrict__ xin =
        reinterpret_cast<const f32x4*>(x) + (size_t)plane * (HW / VEC);
    f32x4* __restrict__ xout =
        reinterpret_cast<f32x4*>(out) + (size_t)plane * (HW / VEC);

    // 4-deep pipeline: named slots, all indices compile-time after unroll.
    f32x4 p0 = xin[0 * THREADS + tid];
    f32x4 p1 = xin[1 * THREADS + tid];
    f32x4 p2 = xin[2 * THREADS + tid];
    f32x4 p3 = xin[3 * THREADS + tid];

    auto body = [&](f32x4& slot, int it) {
        f32x4 v = slot;
        if (it + PIPE < ITERS)
            slot = xin[(it + PIPE) * THREADS + tid];   // prefetch, 4 in flight
        f32x4 r;
        r.x = kan_one(v.x, a_lds, sb, sp, bi);
        r.y = kan_one(v.y, a_lds, sb, sp, bi);
        r.z = kan_one(v.z, a_lds, sb, sp, bi);
        r.w = kan_one(v.w, a_lds, sb, sp, bi);
        __builtin_nontemporal_store(r, &xout[it * THREADS + tid]);
    };

    #pragma unroll
    for (int it = 0; it < ITERS; it += PIPE) {
        body(p0, it + 0);
        body(p1, it + 1);
        body(p2, it + 2);
        body(p3, it + 3);
    }
}

extern "C" void kernel_launch(void* const* d_in, const int* in_sizes, int n_in,
                              void* d_out, int out_size, void* d_ws, size_t ws_size,
                              hipStream_t stream) {
    const float* x          = (const float*)d_in[0];
    const float* coef       = (const float*)d_in[1];
    const float* scale_base = (const float*)d_in[2];
    const float* scale_sp   = (const float*)d_in[3];
    const float* bias       = (const float*)d_in[4];
    float* out              = (float*)d_out;

    const int planes = in_sizes[0] / HW;   // B*C = 2048
    kan_kernel<<<planes, THREADS, 0, stream>>>(x, coef, scale_base, scale_sp, bias, out);
}